// Round 17
// baseline (255.726 us; speedup 1.0000x reference)
//
#include <hip/hip_runtime.h>
#include <hip/hip_bf16.h>

#define B_ 2
#define S_ 2048
#define D_ 1024
#define H_ 16
#define FF_ 4096
#define M_ (B_*S_)   // 4096

using u16 = unsigned short;
using u32 = unsigned int;
typedef __attribute__((ext_vector_type(8))) short short8;
typedef __attribute__((ext_vector_type(4))) float f32x4;
typedef __attribute__((ext_vector_type(16))) float f32x16;
typedef __attribute__((ext_vector_type(4))) unsigned short u16x4;
typedef __attribute__((ext_vector_type(4))) unsigned int u32x4;

static __device__ __forceinline__ u16 f2bf(float f) {
  __hip_bfloat16 h = __float2bfloat16(f);
  return *reinterpret_cast<u16*>(&h);
}
static __device__ __forceinline__ float bf2f(u16 u) {
  __hip_bfloat16 h; *reinterpret_cast<u16*>(&h) = u;
  return __bfloat162float(h);
}

#define GLDS(gp, lp) __builtin_amdgcn_global_load_lds( \
    (const __attribute__((address_space(1))) void*)(gp), \
    (__attribute__((address_space(3))) void*)(lp), 16, 0, 0)

#define MFMA16(a, b, c) __builtin_amdgcn_mfma_f32_16x16x32_bf16(a, b, c, 0, 0, 0)
#define VMC(n) asm volatile("s_waitcnt vmcnt(" #n ")" ::: "memory")
#define BAR() __builtin_amdgcn_s_barrier()
#define CFENCE() asm volatile("" ::: "memory")

// XCD swizzle + 8x8 supertile decode: resident 64 blocks/XCD share one
// 8bm x 8bn supertile -> L2 working set fits the 4MB per-XCD L2.
static __device__ __forceinline__ void tile_decode(
    int lin, int nwg, int gridN, int& bm, int& bn) {
  lin = (lin & 7) * (nwg >> 3) + (lin >> 3);   // bijective XCD swizzle
  int st = lin >> 6, u = lin & 63;
  int nstx = gridN >> 3;
  bm = (st / nstx) * 8 + (u >> 3);
  bn = (st % nstx) * 8 + (u & 7);
}

// ---------------- fused weight conversion + first LayerNorm (one launch) ----------------
__global__ __launch_bounds__(256) void conv_ln(
    const float* __restrict__ Wq, const float* __restrict__ Wk,
    const float* __restrict__ Wv, const float* __restrict__ Wo,
    const float* __restrict__ Wff, const float* __restrict__ Wout,
    u16* __restrict__ wqkv, u16* __restrict__ wo,
    u16* __restrict__ wff, u16* __restrict__ wout,
    const float* __restrict__ x, u16* __restrict__ hbuf) {
  int bid = blockIdx.x;
  if (bid < 16384) {
    const float* src; u16* dst; int off;
    if (bid < 1024)       { src = Wq;   dst = wqkv;           off = bid; }
    else if (bid < 2048)  { src = Wk;   dst = wqkv + 1048576; off = bid - 1024; }
    else if (bid < 3072)  { src = Wv;   dst = wqkv + 2097152; off = bid - 2048; }
    else if (bid < 4096)  { src = Wo;   dst = wo;             off = bid - 3072; }
    else if (bid < 12288) { src = Wff;  dst = wff;            off = bid - 4096; }
    else                  { src = Wout; dst = wout;           off = bid - 12288; }
    int i = off * 256 + threadIdx.x;
    float4 v = reinterpret_cast<const float4*>(src)[i];
    u16x4 o;
    o.x = f2bf(v.x); o.y = f2bf(v.y); o.z = f2bf(v.z); o.w = f2bf(v.w);
    reinterpret_cast<u16x4*>(dst)[i] = o;
  } else {
    int row = bid - 16384;
    int t = threadIdx.x;
    float4 v = reinterpret_cast<const float4*>(x + (size_t)row * D_)[t];
    float s  = v.x + v.y + v.z + v.w;
    float ss = v.x*v.x + v.y*v.y + v.z*v.z + v.w*v.w;
    #pragma unroll
    for (int off = 1; off < 64; off <<= 1) {
      s  += __shfl_xor(s,  off, 64);
      ss += __shfl_xor(ss, off, 64);
    }
    __shared__ float rs[4], rss[4];
    int wid = t >> 6;
    if ((t & 63) == 0) { rs[wid] = s; rss[wid] = ss; }
    __syncthreads();
    s  = rs[0] + rs[1] + rs[2] + rs[3];
    ss = rss[0] + rss[1] + rss[2] + rss[3];
    float mean = s * (1.0f / D_);
    float var  = ss * (1.0f / D_) - mean * mean;
    float r = rsqrtf(var + 1e-5f);
    u16x4 o;
    o.x = f2bf((v.x - mean) * r);
    o.y = f2bf((v.y - mean) * r);
    o.z = f2bf((v.z - mean) * r);
    o.w = f2bf((v.w - mean) * r);
    reinterpret_cast<u16x4*>(hbuf + (size_t)row * D_)[t] = o;
  }
}

// ---------------- LayerNorm (non-parametric), fp32 in -> bf16 out ----------------
__global__ __launch_bounds__(256) void ln_rows(
    const float* __restrict__ x, u16* __restrict__ out) {
  int row = blockIdx.x;
  int t = threadIdx.x;
  float4 v = reinterpret_cast<const float4*>(x + (size_t)row * D_)[t];
  float s  = v.x + v.y + v.z + v.w;
  float ss = v.x*v.x + v.y*v.y + v.z*v.z + v.w*v.w;
  #pragma unroll
  for (int off = 1; off < 64; off <<= 1) {
    s  += __shfl_xor(s,  off, 64);
    ss += __shfl_xor(ss, off, 64);
  }
  __shared__ float rs[4], rss[4];
  int wid = t >> 6;
  if ((t & 63) == 0) { rs[wid] = s; rss[wid] = ss; }
  __syncthreads();
  s  = rs[0] + rs[1] + rs[2] + rs[3];
  ss = rss[0] + rss[1] + rss[2] + rss[3];
  float mean = s * (1.0f / D_);
  float var  = ss * (1.0f / D_) - mean * mean;
  float r = rsqrtf(var + 1e-5f);
  u16x4 o;
  o.x = f2bf((v.x - mean) * r);
  o.y = f2bf((v.y - mean) * r);
  o.z = f2bf((v.z - mean) * r);
  o.w = f2bf((v.w - mean) * r);
  reinterpret_cast<u16x4*>(out + (size_t)row * D_)[t] = o;
}

// ---------------- 128x64 BT GEMM: 2-phase prefetch + swizzle + supertile ----------------
// 48KB LDS -> up to 3 resident blocks/CU. Used for QKV, Wo, Wout.
template<int MODE>
__global__ __launch_bounds__(256, 2) void gemm_bt2h(
    const u16* __restrict__ A, const u16* __restrict__ W,
    void* __restrict__ C, const float* __restrict__ res, int M, int N, int K)
{
  __shared__ u16 lds[24576];  // A: 2 bufs x 16KB; B at +16384: 2 bufs x 8KB
  const int tid = threadIdx.x;
  const int wid = tid >> 6, lane = tid & 63;
  const int g = lane >> 4, c = lane & 15;
  const int gridN = N >> 6;               // 64-col tiles
  int bm, bn;
  tile_decode(blockIdx.x, gridDim.x, gridN, bm, bn);
  const int wm = wid >> 1, wn = wid & 1;
  const int NT = K >> 6;

  f32x4 acc[4][2];
  #pragma unroll
  for (int i = 0; i < 4; i++)
    #pragma unroll
    for (int j = 0; j < 2; j++) acc[i][j] = {0.f, 0.f, 0.f, 0.f};

  auto stage = [&](int sel, int t) {
    const u16* src = sel ? W : A;
    const int tilerow = sel ? bn * 64 : bm * 128;
    char* dst = sel ? (char*)&lds[16384 + (t & 1) * 4096]
                    : (char*)&lds[(t & 1) * 8192];
    const int nldr = sel ? 2 : 4;
    #pragma unroll
    for (int i = 0; i < 4; i++) {
      if (i >= nldr) break;
      int j = i * 256 + tid;
      int row = j >> 3, col16 = j & 7;
      const u16* gp = src + (size_t)(tilerow + row) * K + t * 64 + ((col16 ^ (row & 7)) << 3);
      GLDS(gp, dst + j * 16);
    }
  };

  stage(0, 0); stage(1, 0);
  __syncthreads();

  for (int t = 0; t < NT; t++) {
    const int buf = t & 1;
    if (t + 1 < NT) { stage(0, t + 1); stage(1, t + 1); }

    short8 af[2][4], bfr[2][2];
    #pragma unroll
    for (int ks = 0; ks < 2; ks++)
      #pragma unroll
      for (int m = 0; m < 4; m++) {
        int rh = wm * 64 + m * 16 + c;
        af[ks][m] = *reinterpret_cast<const short8*>(
            &lds[buf * 8192 + rh * 64 + ((((ks << 2) | g) ^ (rh & 7)) << 3)]);
      }
    #pragma unroll
    for (int ks = 0; ks < 2; ks++)
      #pragma unroll
      for (int n = 0; n < 2; n++) {
        int rh = wn * 32 + n * 16 + c;
        bfr[ks][n] = *reinterpret_cast<const short8*>(
            &lds[16384 + buf * 4096 + rh * 64 + ((((ks << 2) | g) ^ (rh & 7)) << 3)]);
      }
    __builtin_amdgcn_s_setprio(1);
    #pragma unroll
    for (int m = 0; m < 4; m++)
      #pragma unroll
      for (int n = 0; n < 2; n++) {
        acc[m][n] = MFMA16(af[0][m], bfr[0][n], acc[m][n]);
        acc[m][n] = MFMA16(af[1][m], bfr[1][n], acc[m][n]);
      }
    __builtin_amdgcn_s_setprio(0);
    __syncthreads();
  }

  #pragma unroll
  for (int m = 0; m < 4; m++)
    #pragma unroll
    for (int n = 0; n < 2; n++)
      #pragma unroll
      for (int r = 0; r < 4; r++) {
        int gr = bm * 128 + wm * 64 + m * 16 + g * 4 + r;
        int gc = bn * 64 + wn * 32 + n * 16 + c;
        size_t idx = (size_t)gr * N + gc;
        float v = acc[m][n][r];
        if (MODE == 0) {
          ((u16*)C)[idx] = f2bf(v);
        } else {
          ((float*)C)[idx] = v + res[idx];
        }
      }
}

// ---------------- fused SwiGLU GEMM (R12/R14-proven: 3-buf 72KB counted-vmcnt) ----------------
__global__ __launch_bounds__(256, 2) void gemm_ff(
    const u16* __restrict__ A, const u16* __restrict__ W,
    u16* __restrict__ Cout, int M, int N, int K)
{
  __shared__ u16 lds[36864];  // A:[0) B1:[12288) B2:[24576), each 3 bufs x 4096
  const int tid = threadIdx.x;
  const int wid = tid >> 6, lane = tid & 63;
  const int g = lane >> 4, c = lane & 15;
  const int gridN = N >> 7;               // 32
  int bm, bn;
  tile_decode(blockIdx.x, gridDim.x, gridN, bm, bn);
  const int wm = wid >> 1, wn = wid & 1;
  const int NT = K >> 5;                  // 32

  f32x4 ac1[4][4], ac2[4][4];
  #pragma unroll
  for (int i = 0; i < 4; i++)
    #pragma unroll
    for (int j = 0; j < 4; j++) { ac1[i][j] = {0.f,0.f,0.f,0.f}; ac2[i][j] = {0.f,0.f,0.f,0.f}; }

  auto stage = [&](int t) {
    #pragma unroll
    for (int sel = 0; sel < 3; sel++) {
      const u16* src = (sel == 0) ? A : W;
      const int rowbase = (sel == 0) ? bm * 128 : (sel == 1 ? bn * 128 : 4096 + bn * 128);
      char* dst = (char*)&lds[sel * 12288 + (t % 3) * 4096];
      #pragma unroll
      for (int i = 0; i < 2; i++) {
        int j = i * 256 + tid;
        int r = j >> 2, cslot = j & 3;
        const u16* gp = src + (size_t)(rowbase + r) * K + t * 32 + ((cslot ^ ((r >> 1) & 3)) * 8);
        GLDS(gp, dst + j * 16);
      }
    }
  };

  stage(0); stage(1);

  for (int t = 0; t < NT; t++) {
    if (t + 1 < NT) { VMC(6); } else { VMC(0); }
    BAR(); CFENCE();
    if (t + 2 < NT) stage(t + 2);

    const int buf = t % 3;
    short8 af[4], b1f[4], b2f[4];
    #pragma unroll
    for (int m = 0; m < 4; m++) {
      int rh = wm * 64 + m * 16 + c;
      af[m] = *reinterpret_cast<const short8*>(
          &lds[buf * 4096 + rh * 32 + ((g ^ ((rh >> 1) & 3)) << 3)]);
    }
    #pragma unroll
    for (int n = 0; n < 4; n++) {
      int rh = wn * 64 + n * 16 + c;
      b1f[n] = *reinterpret_cast<const short8*>(
          &lds[12288 + buf * 4096 + rh * 32 + ((g ^ ((rh >> 1) & 3)) << 3)]);
      b2f[n] = *reinterpret_cast<const short8*>(
          &lds[24576 + buf * 4096 + rh * 32 + ((g ^ ((rh >> 1) & 3)) << 3)]);
    }
    __builtin_amdgcn_s_setprio(1);
    #pragma unroll
    for (int m = 0; m < 4; m++)
      #pragma unroll
      for (int n = 0; n < 4; n++) {
        ac1[m][n] = MFMA16(af[m], b1f[n], ac1[m][n]);
        ac2[m][n] = MFMA16(af[m], b2f[n], ac2[m][n]);
      }
    __builtin_amdgcn_s_setprio(0);
  }

  #pragma unroll
  for (int m = 0; m < 4; m++)
    #pragma unroll
    for (int n = 0; n < 4; n++)
      #pragma unroll
      for (int r = 0; r < 4; r++) {
        int gr = bm * 128 + wm * 64 + m * 16 + g * 4 + r;
        int gc = bn * 128 + wn * 64 + n * 16 + c;
        float v1 = ac1[m][n][r];
        float v2 = ac2[m][n][r];
        float gv = (v1 / (1.0f + __expf(-v1))) * v2;
        Cout[(size_t)gr * N + gc] = f2bf(gv);
      }
}

// ---------------- V transpose: qkv v-section -> vT [B*H, 64, S] ----------------
__global__ __launch_bounds__(256) void transpose_v(
    const u16* __restrict__ qkv, u16* __restrict__ vT) {
  __shared__ u16 t[64][66];
  int bh = blockIdx.y;
  int s0 = blockIdx.x * 64;
  int b = bh >> 4, h = bh & 15;
  int tid = threadIdx.x;
  #pragma unroll
  for (int it = 0; it < 2; it++) {
    int idx = it * 256 + tid;
    int row = idx >> 3;
    int cc  = (idx & 7) * 8;
    const u16* src = qkv + ((size_t)(b * S_ + s0 + row)) * 3072 + 2048 + h * 64 + cc;
    short8 v = *reinterpret_cast<const short8*>(src);
    #pragma unroll
    for (int j = 0; j < 8; j++) t[row][cc + j] = (u16)v[j];
  }
  __syncthreads();
  #pragma unroll
  for (int it = 0; it < 2; it++) {
    int idx = it * 256 + tid;
    int d  = idx >> 3;
    int sc = (idx & 7) * 8;
    short8 o;
    #pragma unroll
    for (int j = 0; j < 8; j++) o[j] = (short)t[sc + j][d];
    *reinterpret_cast<short8*>(vT + ((size_t)bh * 64 + d) * S_ + s0 + sc) = o;
  }
}

// ---------------- split-KV causal flash attention, constant-max softmax ----------------
__global__ __launch_bounds__(256) void attn_split(
    const u16* __restrict__ qkv, const u16* __restrict__ vT,
    u16* __restrict__ pO, float* __restrict__ pML, u16* __restrict__ att) {
  __shared__ u16 Kl[3][2048];
  __shared__ u16 Vl[3][2048];
  const int tid  = threadIdx.x;
  const int lane = tid & 63;
  const int wid  = tid >> 6;
  const int l31  = lane & 31;
  const int half = lane >> 5;

  int lin = blockIdx.x;                       // 0..1279
  int swz = (lin & 7) * 160 + (lin >> 3);     // XCD swizzle: 4 heads/XCD
  int bh  = swz / 40;
  int j   = swz - bh * 40;
  int qq = 15, rem = j;                       // heavy quads first
  while (rem > (qq >> 2)) { rem -= (qq >> 2) + 1; qq--; }
  int ci = rem;
  const int qt  = qq * 4 + wid;
  const int kt0 = ci * 16;
  const int nt  = min(qq * 4 + 3, kt0 + 15) - kt0;   // block-uniform iters-1
  int ubase = (qt < 16) ? qt : (qt < 32) ? 16 + (qt - 16) * 2 + ci
            : (qt < 48) ? 48 + (qt - 32) * 3 + ci : 96 + (qt - 48) * 4 + ci;
  const int punit = bh * 160 + ubase;

  const int b = bh >> 4, hd = bh & 15;
  const int q_base = qt * 32;

  const u16* Qb = qkv + ((size_t)(b * S_ + q_base + l31)) * 3072 + hd * 64;
  const u16* Kb = qkv + (size_t)b * S_ * 3072 + 1024 + hd * 64;
  const u16* Vt = vT + (size_t)bh * 64 * S_;

  short8 qf[4];
  #pragma unroll
  for (int dt = 0; dt < 4; dt++) {
    short8 v = *reinterpret_cast<const short8*>(Qb + dt * 16 + half * 8);
    #pragma unroll
    for (int jj = 0; jj < 8; jj++) v[jj] = (short)f2bf(bf2f((u16)v[jj]) * 0.18033688f);
    qf[dt] = v;
  }

  auto stageKV = [&](int kt, int buf) {
    {
      int row = tid >> 3, cs = tid & 7;
      int c = cs ^ (row & 7);
      const u16* gp = Kb + (size_t)(kt * 32 + row) * 3072 + c * 8;
      GLDS(gp, (char*)&Kl[buf][0] + tid * 16);
    }
    {
      int row = tid >> 2, cs = tid & 3;
      int c = cs ^ ((row >> 1) & 3);
      const u16* gp = Vt + (size_t)row * S_ + kt * 32 + c * 8;
      GLDS(gp, (char*)&Vl[buf][0] + tid * 16);
    }
  };

  f32x16 o0, o1;
  #pragma unroll
  for (int r = 0; r < 16; r++) { o0[r] = 0.f; o1[r] = 0.f; }
  float lsum = 0.f;

  stageKV(kt0, 0);
  if (nt >= 1) { stageKV(kt0 + 1, 1); VMC(2); } else { VMC(0); }
  BAR();

  for (int i = 0; ; i++) {
    const int kt = kt0 + i;
    const int buf = i % 3;
    if (i + 2 <= nt) stageKV(kt0 + i + 2, (i + 2) % 3);  // 2-deep prefetch

    if (kt <= qt) {
      const bool diag = (kt == qt);
      short8 kfr[4], vfr[4];
      #pragma unroll
      for (int dt = 0; dt < 4; dt++) {
        int cs = (dt * 2 + half) ^ (l31 & 7);
        kfr[dt] = *reinterpret_cast<const short8*>((const char*)&Kl[buf][0] + l31 * 128 + cs * 16);
      }
      {
        int r0 = l31, r1 = 32 + l31;
        int x0 = (r0 >> 1) & 3, x1 = (r1 >> 1) & 3;
        vfr[0] = *reinterpret_cast<const short8*>((const char*)&Vl[buf][0] + r0 * 64 + ((half       ^ x0) * 16));
        vfr[1] = *reinterpret_cast<const short8*>((const char*)&Vl[buf][0] + r0 * 64 + (((2 + half) ^ x0) * 16));
        vfr[2] = *reinterpret_cast<const short8*>((const char*)&Vl[buf][0] + r1 * 64 + ((half       ^ x1) * 16));
        vfr[3] = *reinterpret_cast<const short8*>((const char*)&Vl[buf][0] + r1 * 64 + (((2 + half) ^ x1) * 16));
      }

      f32x16 s;
      #pragma unroll
      for (int r = 0; r < 16; r++) s[r] = 0.f;
      __builtin_amdgcn_s_setprio(1);
      #pragma unroll
      for (int dt = 0; dt < 4; dt++)
        s = __builtin_amdgcn_mfma_f32_32x32x16_bf16(kfr[dt], qf[dt], s, 0, 0, 0);
      __builtin_amdgcn_s_setprio(0);

      // constant-max softmax: p = exp2(s), masked -> 0
      float p[16];
      float rs = 0.f;
      #pragma unroll
      for (int r = 0; r < 16; r++) {
        float pv = exp2f(s[r]);
        if (diag) {
          int kloc = half * 4 + (r & 3) + 8 * (r >> 2);
          if (kloc > l31) pv = 0.f;
        }
        p[r] = pv;
        rs += pv;
      }
      rs += __shfl_xor(rs, 32, 64);
      lsum += rs;

      u32 pk[8], sp[8];
      #pragma unroll
      for (int ii = 0; ii < 8; ii++) {
        pk[ii] = (u32)f2bf(p[2 * ii]) | ((u32)f2bf(p[2 * ii + 1]) << 16);
        sp[ii] = (u32)__shfl_xor((int)pk[ii], 32, 64);
      }
      u32x4 a0 = { half ? sp[2] : pk[0], half ? sp[3] : pk[1],
                   half ? pk[2] : sp[0], half ? pk[3] : sp[1] };
      u32x4 a1 = { half ? sp[6] : pk[4], half ? sp[7] : pk[5],
                   half ? pk[6] : sp[4], half ? pk[7] : sp[5] };
      short8 pa0 = *reinterpret_cast<short8*>(&a0);
      short8 pa1 = *reinterpret_cast<short8*>(&a1);

      __builtin_amdgcn_s_setprio(1);
      o0 = __builtin_amdgcn_mfma_f32_32x32x16_bf16(pa0, vfr[0], o0, 0, 0, 0);
      o0 = __builtin_amdgcn_mfma_f32_32x32x16_bf16(pa1, vfr[1], o0, 0, 0, 0);
      o1 = __builtin_amdgcn_mfma_f32_32x32x16_bf16(pa0, vfr[2], o1, 0, 0, 0);
      o1 = __builtin_amdgcn_mfma_f32_32x32x16_bf16(pa1, vfr[3], o1, 0, 0, 0);
      __builtin_amdgcn_s_setprio(0);
    }

    if (i == nt) break;
    if (i + 2 <= nt) { VMC(2); } else { VMC(0); }
    BAR();
  }

  if (qt < 16) {
    #pragma unroll
    for (int r = 0; r < 16; r++) {
      int row = (r & 3) + 8 * (r >> 2) + 4 * half;
      float inv = 1.0f / __shfl(lsum, row, 64);
      size_t base = ((size_t)(b * S_ + q_base + row)) * D_ + hd * 64 + l31;
      att[base]      = f2bf(o0[r] * inv);
      att[base + 32] = f2bf(o1[r] * inv);
    }
  } else {
    #pragma unroll
    for (int r = 0; r < 16; r++) {
      int row = (r & 3) + 8 * (r >> 2) + 4 * half;
      pO[(size_t)punit * 2048 + row * 64 + l31]      = f2bf(o0[r]);
      pO[(size_t)punit * 2048 + row * 64 + 32 + l31] = f2bf(o1[r]);
    }
    if (half == 0) pML[punit * 32 + l31] = lsum;
  }
}

// ---------------- combine partials -> att (plain sum; qt >= 16 only) ----------------
__global__ __launch_bounds__(256) void attn_combine(
    const u16* __restrict__ pO, const float* __restrict__ pML,
    u16* __restrict__ att) {
  int gw = blockIdx.x;                 // 0..1535
  int bh = gw / 48, qt = 16 + gw % 48;
  int b = bh >> 4, hd = bh & 15;
  int nc = (qt >> 4) + 1;              // 2..4
  int base = (qt < 32) ? 16 + (qt - 16) * 2
           : (qt < 48) ? 48 + (qt - 32) * 3 : 96 + (qt - 48) * 4;
  int p0 = bh * 160 + base;
  int q  = threadIdx.x >> 3;
  int d  = (threadIdx.x & 7) * 8;

  float L = pML[p0 * 32 + q] + pML[(p0 + 1) * 32 + q];
  if (nc > 2) L += pML[(p0 + 2) * 32 + q];
  if (nc > 3) L += pML[(p0 + 3) * 32 + q];
  float invL = 1.0f / L;

  float o[8];
  short8 v0 = *reinterpret_cast<const short8*>(&pO[(size_t)p0 * 2048 + q * 64 + d]);
  short8 v1 = *reinterpret_cast<const short8*>(&pO[(size_t)(p0 + 1) * 2048 + q * 64 + d]);
  #pragma unroll
  for (int jj = 0; jj < 8; jj++) o[jj] = bf2f((u16)v0[jj]) + bf2f((u16)v1[jj]);
  if (nc > 2) {
    short8 v = *reinterpret_cast<const short8*>(&pO[(size_t)(p0 + 2) * 2048 + q * 64 + d]);
    #pragma unroll
    for (int jj = 0; jj < 8; jj++) o[jj] += bf2f((u16)v[jj]);
  }
  if (nc > 3) {
    short8 v = *reinterpret_cast<const short8*>(&pO[(size_t)(p0 + 3) * 2048 + q * 64 + d]);
    #pragma unroll
    for (int jj = 0; jj < 8; jj++) o[jj] += bf2f((u16)v[jj]);
  }
  short8 ov;
  #pragma unroll
  for (int jj = 0; jj < 8; jj++) ov[jj] = (short)f2bf(o[jj] * invL);
  *reinterpret_cast<short8*>(
      &att[((size_t)(b * S_ + qt * 32 + q)) * D_ + hd * 64 + d]) = ov;
}

// ---------------- host launch ----------------
extern "C" void kernel_launch(void* const* d_in, const int* in_sizes, int n_in,
                              void* d_out, int out_size, void* d_ws, size_t ws_size,
                              hipStream_t stream) {
  (void)in_sizes; (void)n_in; (void)out_size; (void)ws_size;
  const float* x    = (const float*)d_in[0];
  const float* Wq   = (const float*)d_in[1];
  const float* Wk   = (const float*)d_in[2];
  const float* Wv   = (const float*)d_in[3];
  const float* Wo   = (const float*)d_in[4];
  const float* Wff  = (const float*)d_in[5];
  const float* Wout = (const float*)d_in[6];
  float* out = (float*)d_out;

  char* ws = (char*)d_ws;
  u16*   wqkv = (u16*)(ws);                    // [3072,1024] bf16, 6MB
  u16*   wo   = (u16*)(ws + 6291456);          // [1024,1024], 2MB
  u16*   wff  = (u16*)(ws + 8388608);          // [8192,1024], 16MB
  u16*   wout = (u16*)(ws + 25165824);         // [1024,4096], 8MB
  float* x1   = (float*)(ws + 33554432);       // [4096,1024] f32, 16MB
  char*  P    = ws + 50331648;                 // reuse pool
  u16*   hbuf = (u16*)(P);                     // [4096,1024], 8MB
  u16*   qkv  = (u16*)(P + 8388608);           // [4096,3072], 24MB
  u16*   vT   = (u16*)(P + 33554432);          // [32,64,2048], 8MB
  u16*   att  = (u16*)(P + 41943040);          // [4096,1024], 8MB
  u16*   pO   = (u16*)(P + 50331648);          // [5120,2048] bf16, 21MB (attn phase)
  float* pML  = (float*)(P + 71303168);        // [5120,32] f32, 640KB
  u16*   h2   = (u16*)(P);                     // reuse hbuf slot
  u16*   gbuf = (u16*)(P + 41943040);          // [4096,4096], 32MB (over att+pO head)

  conv_ln<<<20480, 256, 0, stream>>>(Wq, Wk, Wv, Wo, Wff, Wout,
                                     wqkv, wo, wff, wout, x, hbuf);

  gemm_bt2h<0><<<dim3(1536), 256, 0, stream>>>(hbuf, wqkv, qkv, nullptr, M_, 3072, 1024);
  transpose_v<<<dim3(32, 32), 256, 0, stream>>>(qkv, vT);
  attn_split<<<dim3(1280), 256, 0, stream>>>(qkv, vT, pO, pML, att);
  attn_combine<<<dim3(1536), 256, 0, stream>>>(pO, pML, att);
  gemm_bt2h<1><<<dim3(512), 256, 0, stream>>>(att, wo, x1, x, M_, 1024, 1024);

  ln_rows<<<M_, 256, 0, stream>>>(x1, h2);
  gemm_ff<<<dim3(1024), 256, 0, stream>>>(h2, wff, gbuf, M_, 4096, 1024);
  gemm_bt2h<1><<<dim3(512), 256, 0, stream>>>(gbuf, wout, out, x1, M_, 1024, 4096);
}

// Round 18
// 252.773 us; speedup vs baseline: 1.0117x; 1.0117x over previous
//
#include <hip/hip_runtime.h>
#include <hip/hip_bf16.h>

#define B_ 2
#define S_ 2048
#define D_ 1024
#define H_ 16
#define FF_ 4096
#define M_ (B_*S_)   // 4096

using u16 = unsigned short;
using u32 = unsigned int;
typedef __attribute__((ext_vector_type(8))) short short8;
typedef __attribute__((ext_vector_type(4))) float f32x4;
typedef __attribute__((ext_vector_type(16))) float f32x16;
typedef __attribute__((ext_vector_type(4))) unsigned short u16x4;
typedef __attribute__((ext_vector_type(4))) unsigned int u32x4;

static __device__ __forceinline__ u16 f2bf(float f) {
  __hip_bfloat16 h = __float2bfloat16(f);
  return *reinterpret_cast<u16*>(&h);
}
static __device__ __forceinline__ float bf2f(u16 u) {
  __hip_bfloat16 h; *reinterpret_cast<u16*>(&h) = u;
  return __bfloat162float(h);
}

#define GLDS(gp, lp) __builtin_amdgcn_global_load_lds( \
    (const __attribute__((address_space(1))) void*)(gp), \
    (__attribute__((address_space(3))) void*)(lp), 16, 0, 0)

#define MFMA16(a, b, c) __builtin_amdgcn_mfma_f32_16x16x32_bf16(a, b, c, 0, 0, 0)
#define VMC(n) asm volatile("s_waitcnt vmcnt(" #n ")" ::: "memory")
#define BAR() __builtin_amdgcn_s_barrier()
#define CFENCE() asm volatile("" ::: "memory")

// XCD swizzle + 8x8 supertile decode: resident 64 blocks/XCD share one
// 8bm x 8bn supertile -> L2 working set fits the 4MB per-XCD L2.
static __device__ __forceinline__ void tile_decode(
    int lin, int nwg, int gridN, int& bm, int& bn) {
  lin = (lin & 7) * (nwg >> 3) + (lin >> 3);   // bijective XCD swizzle
  int st = lin >> 6, u = lin & 63;
  int nstx = gridN >> 3;
  bm = (st / nstx) * 8 + (u >> 3);
  bn = (st % nstx) * 8 + (u & 7);
}

// ---------------- fused weight conversion + first LayerNorm (one launch) ----------------
__global__ __launch_bounds__(256) void conv_ln(
    const float* __restrict__ Wq, const float* __restrict__ Wk,
    const float* __restrict__ Wv, const float* __restrict__ Wo,
    const float* __restrict__ Wff, const float* __restrict__ Wout,
    u16* __restrict__ wqkv, u16* __restrict__ wo,
    u16* __restrict__ wff, u16* __restrict__ wout,
    const float* __restrict__ x, u16* __restrict__ hbuf) {
  int bid = blockIdx.x;
  if (bid < 16384) {
    const float* src; u16* dst; int off;
    if (bid < 1024)       { src = Wq;   dst = wqkv;           off = bid; }
    else if (bid < 2048)  { src = Wk;   dst = wqkv + 1048576; off = bid - 1024; }
    else if (bid < 3072)  { src = Wv;   dst = wqkv + 2097152; off = bid - 2048; }
    else if (bid < 4096)  { src = Wo;   dst = wo;             off = bid - 3072; }
    else if (bid < 12288) { src = Wff;  dst = wff;            off = bid - 4096; }
    else                  { src = Wout; dst = wout;           off = bid - 12288; }
    int i = off * 256 + threadIdx.x;
    float4 v = reinterpret_cast<const float4*>(src)[i];
    u16x4 o;
    o.x = f2bf(v.x); o.y = f2bf(v.y); o.z = f2bf(v.z); o.w = f2bf(v.w);
    reinterpret_cast<u16x4*>(dst)[i] = o;
  } else {
    int row = bid - 16384;
    int t = threadIdx.x;
    float4 v = reinterpret_cast<const float4*>(x + (size_t)row * D_)[t];
    float s  = v.x + v.y + v.z + v.w;
    float ss = v.x*v.x + v.y*v.y + v.z*v.z + v.w*v.w;
    #pragma unroll
    for (int off = 1; off < 64; off <<= 1) {
      s  += __shfl_xor(s,  off, 64);
      ss += __shfl_xor(ss, off, 64);
    }
    __shared__ float rs[4], rss[4];
    int wid = t >> 6;
    if ((t & 63) == 0) { rs[wid] = s; rss[wid] = ss; }
    __syncthreads();
    s  = rs[0] + rs[1] + rs[2] + rs[3];
    ss = rss[0] + rss[1] + rss[2] + rss[3];
    float mean = s * (1.0f / D_);
    float var  = ss * (1.0f / D_) - mean * mean;
    float r = rsqrtf(var + 1e-5f);
    u16x4 o;
    o.x = f2bf((v.x - mean) * r);
    o.y = f2bf((v.y - mean) * r);
    o.z = f2bf((v.z - mean) * r);
    o.w = f2bf((v.w - mean) * r);
    reinterpret_cast<u16x4*>(hbuf + (size_t)row * D_)[t] = o;
  }
}

// ---------------- LayerNorm (non-parametric), fp32 in -> bf16 out ----------------
__global__ __launch_bounds__(256) void ln_rows(
    const float* __restrict__ x, u16* __restrict__ out) {
  int row = blockIdx.x;
  int t = threadIdx.x;
  float4 v = reinterpret_cast<const float4*>(x + (size_t)row * D_)[t];
  float s  = v.x + v.y + v.z + v.w;
  float ss = v.x*v.x + v.y*v.y + v.z*v.z + v.w*v.w;
  #pragma unroll
  for (int off = 1; off < 64; off <<= 1) {
    s  += __shfl_xor(s,  off, 64);
    ss += __shfl_xor(ss, off, 64);
  }
  __shared__ float rs[4], rss[4];
  int wid = t >> 6;
  if ((t & 63) == 0) { rs[wid] = s; rss[wid] = ss; }
  __syncthreads();
  s  = rs[0] + rs[1] + rs[2] + rs[3];
  ss = rss[0] + rss[1] + rss[2] + rss[3];
  float mean = s * (1.0f / D_);
  float var  = ss * (1.0f / D_) - mean * mean;
  float r = rsqrtf(var + 1e-5f);
  u16x4 o;
  o.x = f2bf((v.x - mean) * r);
  o.y = f2bf((v.y - mean) * r);
  o.z = f2bf((v.z - mean) * r);
  o.w = f2bf((v.w - mean) * r);
  reinterpret_cast<u16x4*>(out + (size_t)row * D_)[t] = o;
}

// ---------------- 128x128 BT GEMM v2 (QKV): 2-phase prefetch + swizzle + supertile ----------------
template<int MODE>
__global__ __launch_bounds__(256, 2) void gemm_bt2(
    const u16* __restrict__ A, const u16* __restrict__ W,
    void* __restrict__ C, const float* __restrict__ res, int M, int N, int K)
{
  __shared__ u16 lds[32768];
  const int tid = threadIdx.x;
  const int wid = tid >> 6, lane = tid & 63;
  const int g = lane >> 4, c = lane & 15;
  const int gridN = N >> 7;
  int bm, bn;
  tile_decode(blockIdx.x, gridDim.x, gridN, bm, bn);
  const int wm = wid >> 1, wn = wid & 1;
  const int NT = K >> 6;

  f32x4 acc[4][4];
  #pragma unroll
  for (int i = 0; i < 4; i++)
    #pragma unroll
    for (int j = 0; j < 4; j++) acc[i][j] = {0.f, 0.f, 0.f, 0.f};

  auto stage = [&](int sel, int t) {
    const u16* src = sel ? W : A;
    const int tilerow = (sel ? bn : bm) * 128;
    char* dst = (char*)&lds[sel * 16384 + (t & 1) * 8192];
    #pragma unroll
    for (int i = 0; i < 4; i++) {
      int j = i * 256 + tid;
      int row = j >> 3, col16 = j & 7;
      const u16* gp = src + (size_t)(tilerow + row) * K + t * 64 + ((col16 ^ (row & 7)) << 3);
      GLDS(gp, dst + j * 16);
    }
  };

  stage(0, 0); stage(1, 0);
  __syncthreads();

  for (int t = 0; t < NT; t++) {
    const int buf = t & 1;
    if (t + 1 < NT) { stage(0, t + 1); stage(1, t + 1); }

    short8 af[2][4], bfr[2][4];
    #pragma unroll
    for (int ks = 0; ks < 2; ks++)
      #pragma unroll
      for (int m = 0; m < 4; m++) {
        int rh = wm * 64 + m * 16 + c;
        af[ks][m] = *reinterpret_cast<const short8*>(
            &lds[buf * 8192 + rh * 64 + ((((ks << 2) | g) ^ (rh & 7)) << 3)]);
      }
    #pragma unroll
    for (int ks = 0; ks < 2; ks++)
      #pragma unroll
      for (int n = 0; n < 4; n++) {
        int rh = wn * 64 + n * 16 + c;
        bfr[ks][n] = *reinterpret_cast<const short8*>(
            &lds[16384 + buf * 8192 + rh * 64 + ((((ks << 2) | g) ^ (rh & 7)) << 3)]);
      }
    __builtin_amdgcn_s_setprio(1);
    #pragma unroll
    for (int m = 0; m < 4; m++)
      #pragma unroll
      for (int n = 0; n < 4; n++) {
        acc[m][n] = MFMA16(af[0][m], bfr[0][n], acc[m][n]);
        acc[m][n] = MFMA16(af[1][m], bfr[1][n], acc[m][n]);
      }
    __builtin_amdgcn_s_setprio(0);
    __syncthreads();
  }

  #pragma unroll
  for (int m = 0; m < 4; m++)
    #pragma unroll
    for (int n = 0; n < 4; n++)
      #pragma unroll
      for (int r = 0; r < 4; r++) {
        int gr = bm * 128 + wm * 64 + m * 16 + g * 4 + r;
        int gc = bn * 128 + wn * 64 + n * 16 + c;
        size_t idx = (size_t)gr * N + gc;
        float v = acc[m][n][r];
        if (MODE == 0) {
          ((u16*)C)[idx] = f2bf(v);
        } else {
          ((float*)C)[idx] = v + res[idx];
        }
      }
}

// ---------------- 128x64 BT GEMM (Wo/Wout): grid 2x -> 2 blocks/CU TLP ----------------
template<int MODE>
__global__ __launch_bounds__(256, 2) void gemm_bt2h(
    const u16* __restrict__ A, const u16* __restrict__ W,
    void* __restrict__ C, const float* __restrict__ res, int M, int N, int K)
{
  __shared__ u16 lds[24576];  // A: 2 bufs x 16KB; B at +16384: 2 bufs x 8KB
  const int tid = threadIdx.x;
  const int wid = tid >> 6, lane = tid & 63;
  const int g = lane >> 4, c = lane & 15;
  const int gridN = N >> 6;               // 64-col tiles
  int bm, bn;
  tile_decode(blockIdx.x, gridDim.x, gridN, bm, bn);
  const int wm = wid >> 1, wn = wid & 1;
  const int NT = K >> 6;

  f32x4 acc[4][2];
  #pragma unroll
  for (int i = 0; i < 4; i++)
    #pragma unroll
    for (int j = 0; j < 2; j++) acc[i][j] = {0.f, 0.f, 0.f, 0.f};

  auto stage = [&](int sel, int t) {
    const u16* src = sel ? W : A;
    const int tilerow = sel ? bn * 64 : bm * 128;
    char* dst = sel ? (char*)&lds[16384 + (t & 1) * 4096]
                    : (char*)&lds[(t & 1) * 8192];
    const int nldr = sel ? 2 : 4;
    #pragma unroll
    for (int i = 0; i < 4; i++) {
      if (i >= nldr) break;
      int j = i * 256 + tid;
      int row = j >> 3, col16 = j & 7;
      const u16* gp = src + (size_t)(tilerow + row) * K + t * 64 + ((col16 ^ (row & 7)) << 3);
      GLDS(gp, dst + j * 16);
    }
  };

  stage(0, 0); stage(1, 0);
  __syncthreads();

  for (int t = 0; t < NT; t++) {
    const int buf = t & 1;
    if (t + 1 < NT) { stage(0, t + 1); stage(1, t + 1); }

    short8 af[2][4], bfr[2][2];
    #pragma unroll
    for (int ks = 0; ks < 2; ks++)
      #pragma unroll
      for (int m = 0; m < 4; m++) {
        int rh = wm * 64 + m * 16 + c;
        af[ks][m] = *reinterpret_cast<const short8*>(
            &lds[buf * 8192 + rh * 64 + ((((ks << 2) | g) ^ (rh & 7)) << 3)]);
      }
    #pragma unroll
    for (int ks = 0; ks < 2; ks++)
      #pragma unroll
      for (int n = 0; n < 2; n++) {
        int rh = wn * 32 + n * 16 + c;
        bfr[ks][n] = *reinterpret_cast<const short8*>(
            &lds[16384 + buf * 4096 + rh * 64 + ((((ks << 2) | g) ^ (rh & 7)) << 3)]);
      }
    __builtin_amdgcn_s_setprio(1);
    #pragma unroll
    for (int m = 0; m < 4; m++)
      #pragma unroll
      for (int n = 0; n < 2; n++) {
        acc[m][n] = MFMA16(af[0][m], bfr[0][n], acc[m][n]);
        acc[m][n] = MFMA16(af[1][m], bfr[1][n], acc[m][n]);
      }
    __builtin_amdgcn_s_setprio(0);
    __syncthreads();
  }

  #pragma unroll
  for (int m = 0; m < 4; m++)
    #pragma unroll
    for (int n = 0; n < 2; n++)
      #pragma unroll
      for (int r = 0; r < 4; r++) {
        int gr = bm * 128 + wm * 64 + m * 16 + g * 4 + r;
        int gc = bn * 64 + wn * 32 + n * 16 + c;
        size_t idx = (size_t)gr * N + gc;
        float v = acc[m][n][r];
        if (MODE == 0) {
          ((u16*)C)[idx] = f2bf(v);
        } else {
          ((float*)C)[idx] = v + res[idx];
        }
      }
}

// ---------------- fused SwiGLU GEMM (R12/R14-proven: 3-buf 72KB counted-vmcnt) ----------------
__global__ __launch_bounds__(256, 2) void gemm_ff(
    const u16* __restrict__ A, const u16* __restrict__ W,
    u16* __restrict__ Cout, int M, int N, int K)
{
  __shared__ u16 lds[36864];  // A:[0) B1:[12288) B2:[24576), each 3 bufs x 4096
  const int tid = threadIdx.x;
  const int wid = tid >> 6, lane = tid & 63;
  const int g = lane >> 4, c = lane & 15;
  const int gridN = N >> 7;               // 32
  int bm, bn;
  tile_decode(blockIdx.x, gridDim.x, gridN, bm, bn);
  const int wm = wid >> 1, wn = wid & 1;
  const int NT = K >> 5;                  // 32

  f32x4 ac1[4][4], ac2[4][4];
  #pragma unroll
  for (int i = 0; i < 4; i++)
    #pragma unroll
    for (int j = 0; j < 4; j++) { ac1[i][j] = {0.f,0.f,0.f,0.f}; ac2[i][j] = {0.f,0.f,0.f,0.f}; }

  auto stage = [&](int t) {
    #pragma unroll
    for (int sel = 0; sel < 3; sel++) {
      const u16* src = (sel == 0) ? A : W;
      const int rowbase = (sel == 0) ? bm * 128 : (sel == 1 ? bn * 128 : 4096 + bn * 128);
      char* dst = (char*)&lds[sel * 12288 + (t % 3) * 4096];
      #pragma unroll
      for (int i = 0; i < 2; i++) {
        int j = i * 256 + tid;
        int r = j >> 2, cslot = j & 3;
        const u16* gp = src + (size_t)(rowbase + r) * K + t * 32 + ((cslot ^ ((r >> 1) & 3)) * 8);
        GLDS(gp, dst + j * 16);
      }
    }
  };

  stage(0); stage(1);

  for (int t = 0; t < NT; t++) {
    if (t + 1 < NT) { VMC(6); } else { VMC(0); }
    BAR(); CFENCE();
    if (t + 2 < NT) stage(t + 2);

    const int buf = t % 3;
    short8 af[4], b1f[4], b2f[4];
    #pragma unroll
    for (int m = 0; m < 4; m++) {
      int rh = wm * 64 + m * 16 + c;
      af[m] = *reinterpret_cast<const short8*>(
          &lds[buf * 4096 + rh * 32 + ((g ^ ((rh >> 1) & 3)) << 3)]);
    }
    #pragma unroll
    for (int n = 0; n < 4; n++) {
      int rh = wn * 64 + n * 16 + c;
      b1f[n] = *reinterpret_cast<const short8*>(
          &lds[12288 + buf * 4096 + rh * 32 + ((g ^ ((rh >> 1) & 3)) << 3)]);
      b2f[n] = *reinterpret_cast<const short8*>(
          &lds[24576 + buf * 4096 + rh * 32 + ((g ^ ((rh >> 1) & 3)) << 3)]);
    }
    __builtin_amdgcn_s_setprio(1);
    #pragma unroll
    for (int m = 0; m < 4; m++)
      #pragma unroll
      for (int n = 0; n < 4; n++) {
        ac1[m][n] = MFMA16(af[m], b1f[n], ac1[m][n]);
        ac2[m][n] = MFMA16(af[m], b2f[n], ac2[m][n]);
      }
    __builtin_amdgcn_s_setprio(0);
  }

  #pragma unroll
  for (int m = 0; m < 4; m++)
    #pragma unroll
    for (int n = 0; n < 4; n++)
      #pragma unroll
      for (int r = 0; r < 4; r++) {
        int gr = bm * 128 + wm * 64 + m * 16 + g * 4 + r;
        int gc = bn * 128 + wn * 64 + n * 16 + c;
        float v1 = ac1[m][n][r];
        float v2 = ac2[m][n][r];
        float gv = (v1 / (1.0f + __expf(-v1))) * v2;
        Cout[(size_t)gr * N + gc] = f2bf(gv);
      }
}

// ---------------- V transpose: qkv v-section -> vT [B*H, 64, S] ----------------
__global__ __launch_bounds__(256) void transpose_v(
    const u16* __restrict__ qkv, u16* __restrict__ vT) {
  __shared__ u16 t[64][66];
  int bh = blockIdx.y;
  int s0 = blockIdx.x * 64;
  int b = bh >> 4, h = bh & 15;
  int tid = threadIdx.x;
  #pragma unroll
  for (int it = 0; it < 2; it++) {
    int idx = it * 256 + tid;
    int row = idx >> 3;
    int cc  = (idx & 7) * 8;
    const u16* src = qkv + ((size_t)(b * S_ + s0 + row)) * 3072 + 2048 + h * 64 + cc;
    short8 v = *reinterpret_cast<const short8*>(src);
    #pragma unroll
    for (int j = 0; j < 8; j++) t[row][cc + j] = (u16)v[j];
  }
  __syncthreads();
  #pragma unroll
  for (int it = 0; it < 2; it++) {
    int idx = it * 256 + tid;
    int d  = idx >> 3;
    int sc = (idx & 7) * 8;
    short8 o;
    #pragma unroll
    for (int j = 0; j < 8; j++) o[j] = (short)t[sc + j][d];
    *reinterpret_cast<short8*>(vT + ((size_t)bh * 64 + d) * S_ + s0 + sc) = o;
  }
}

// ---------------- split-KV causal flash attention, constant-max softmax ----------------
__global__ __launch_bounds__(256) void attn_split(
    const u16* __restrict__ qkv, const u16* __restrict__ vT,
    u16* __restrict__ pO, float* __restrict__ pML, u16* __restrict__ att) {
  __shared__ u16 Kl[3][2048];
  __shared__ u16 Vl[3][2048];
  const int tid  = threadIdx.x;
  const int lane = tid & 63;
  const int wid  = tid >> 6;
  const int l31  = lane & 31;
  const int half = lane >> 5;

  int lin = blockIdx.x;                       // 0..1279
  int swz = (lin & 7) * 160 + (lin >> 3);     // XCD swizzle: 4 heads/XCD
  int bh  = swz / 40;
  int j   = swz - bh * 40;
  int qq = 15, rem = j;                       // heavy quads first
  while (rem > (qq >> 2)) { rem -= (qq >> 2) + 1; qq--; }
  int ci = rem;
  const int qt  = qq * 4 + wid;
  const int kt0 = ci * 16;
  const int nt  = min(qq * 4 + 3, kt0 + 15) - kt0;   // block-uniform iters-1
  int ubase = (qt < 16) ? qt : (qt < 32) ? 16 + (qt - 16) * 2 + ci
            : (qt < 48) ? 48 + (qt - 32) * 3 + ci : 96 + (qt - 48) * 4 + ci;
  const int punit = bh * 160 + ubase;

  const int b = bh >> 4, hd = bh & 15;
  const int q_base = qt * 32;

  const u16* Qb = qkv + ((size_t)(b * S_ + q_base + l31)) * 3072 + hd * 64;
  const u16* Kb = qkv + (size_t)b * S_ * 3072 + 1024 + hd * 64;
  const u16* Vt = vT + (size_t)bh * 64 * S_;

  short8 qf[4];
  #pragma unroll
  for (int dt = 0; dt < 4; dt++) {
    short8 v = *reinterpret_cast<const short8*>(Qb + dt * 16 + half * 8);
    #pragma unroll
    for (int jj = 0; jj < 8; jj++) v[jj] = (short)f2bf(bf2f((u16)v[jj]) * 0.18033688f);
    qf[dt] = v;
  }

  auto stageKV = [&](int kt, int buf) {
    {
      int row = tid >> 3, cs = tid & 7;
      int c = cs ^ (row & 7);
      const u16* gp = Kb + (size_t)(kt * 32 + row) * 3072 + c * 8;
      GLDS(gp, (char*)&Kl[buf][0] + tid * 16);
    }
    {
      int row = tid >> 2, cs = tid & 3;
      int c = cs ^ ((row >> 1) & 3);
      const u16* gp = Vt + (size_t)row * S_ + kt * 32 + c * 8;
      GLDS(gp, (char*)&Vl[buf][0] + tid * 16);
    }
  };

  f32x16 o0, o1;
  #pragma unroll
  for (int r = 0; r < 16; r++) { o0[r] = 0.f; o1[r] = 0.f; }
  float lsum = 0.f;

  stageKV(kt0, 0);
  if (nt >= 1) { stageKV(kt0 + 1, 1); VMC(2); } else { VMC(0); }
  BAR();

  for (int i = 0; ; i++) {
    const int kt = kt0 + i;
    const int buf = i % 3;
    if (i + 2 <= nt) stageKV(kt0 + i + 2, (i + 2) % 3);  // 2-deep prefetch

    if (kt <= qt) {
      const bool diag = (kt == qt);
      short8 kfr[4], vfr[4];
      #pragma unroll
      for (int dt = 0; dt < 4; dt++) {
        int cs = (dt * 2 + half) ^ (l31 & 7);
        kfr[dt] = *reinterpret_cast<const short8*>((const char*)&Kl[buf][0] + l31 * 128 + cs * 16);
      }
      {
        int r0 = l31, r1 = 32 + l31;
        int x0 = (r0 >> 1) & 3, x1 = (r1 >> 1) & 3;
        vfr[0] = *reinterpret_cast<const short8*>((const char*)&Vl[buf][0] + r0 * 64 + ((half       ^ x0) * 16));
        vfr[1] = *reinterpret_cast<const short8*>((const char*)&Vl[buf][0] + r0 * 64 + (((2 + half) ^ x0) * 16));
        vfr[2] = *reinterpret_cast<const short8*>((const char*)&Vl[buf][0] + r1 * 64 + ((half       ^ x1) * 16));
        vfr[3] = *reinterpret_cast<const short8*>((const char*)&Vl[buf][0] + r1 * 64 + (((2 + half) ^ x1) * 16));
      }

      f32x16 s;
      #pragma unroll
      for (int r = 0; r < 16; r++) s[r] = 0.f;
      __builtin_amdgcn_s_setprio(1);
      #pragma unroll
      for (int dt = 0; dt < 4; dt++)
        s = __builtin_amdgcn_mfma_f32_32x32x16_bf16(kfr[dt], qf[dt], s, 0, 0, 0);
      __builtin_amdgcn_s_setprio(0);

      // constant-max softmax: p = exp2(s), masked -> 0
      float p[16];
      float rs = 0.f;
      #pragma unroll
      for (int r = 0; r < 16; r++) {
        float pv = exp2f(s[r]);
        if (diag) {
          int kloc = half * 4 + (r & 3) + 8 * (r >> 2);
          if (kloc > l31) pv = 0.f;
        }
        p[r] = pv;
        rs += pv;
      }
      rs += __shfl_xor(rs, 32, 64);
      lsum += rs;

      u32 pk[8], sp[8];
      #pragma unroll
      for (int ii = 0; ii < 8; ii++) {
        pk[ii] = (u32)f2bf(p[2 * ii]) | ((u32)f2bf(p[2 * ii + 1]) << 16);
        sp[ii] = (u32)__shfl_xor((int)pk[ii], 32, 64);
      }
      u32x4 a0 = { half ? sp[2] : pk[0], half ? sp[3] : pk[1],
                   half ? pk[2] : sp[0], half ? pk[3] : sp[1] };
      u32x4 a1 = { half ? sp[6] : pk[4], half ? sp[7] : pk[5],
                   half ? pk[6] : sp[4], half ? pk[7] : sp[5] };
      short8 pa0 = *reinterpret_cast<short8*>(&a0);
      short8 pa1 = *reinterpret_cast<short8*>(&a1);

      __builtin_amdgcn_s_setprio(1);
      o0 = __builtin_amdgcn_mfma_f32_32x32x16_bf16(pa0, vfr[0], o0, 0, 0, 0);
      o0 = __builtin_amdgcn_mfma_f32_32x32x16_bf16(pa1, vfr[1], o0, 0, 0, 0);
      o1 = __builtin_amdgcn_mfma_f32_32x32x16_bf16(pa0, vfr[2], o1, 0, 0, 0);
      o1 = __builtin_amdgcn_mfma_f32_32x32x16_bf16(pa1, vfr[3], o1, 0, 0, 0);
      __builtin_amdgcn_s_setprio(0);
    }

    if (i == nt) break;
    if (i + 2 <= nt) { VMC(2); } else { VMC(0); }
    BAR();
  }

  if (qt < 16) {
    #pragma unroll
    for (int r = 0; r < 16; r++) {
      int row = (r & 3) + 8 * (r >> 2) + 4 * half;
      float inv = 1.0f / __shfl(lsum, row, 64);
      size_t base = ((size_t)(b * S_ + q_base + row)) * D_ + hd * 64 + l31;
      att[base]      = f2bf(o0[r] * inv);
      att[base + 32] = f2bf(o1[r] * inv);
    }
  } else {
    #pragma unroll
    for (int r = 0; r < 16; r++) {
      int row = (r & 3) + 8 * (r >> 2) + 4 * half;
      pO[(size_t)punit * 2048 + row * 64 + l31]      = f2bf(o0[r]);
      pO[(size_t)punit * 2048 + row * 64 + 32 + l31] = f2bf(o1[r]);
    }
    if (half == 0) pML[punit * 32 + l31] = lsum;
  }
}

// ---------------- combine partials -> att (plain sum; qt >= 16 only) ----------------
__global__ __launch_bounds__(256) void attn_combine(
    const u16* __restrict__ pO, const float* __restrict__ pML,
    u16* __restrict__ att) {
  int gw = blockIdx.x;                 // 0..1535
  int bh = gw / 48, qt = 16 + gw % 48;
  int b = bh >> 4, hd = bh & 15;
  int nc = (qt >> 4) + 1;              // 2..4
  int base = (qt < 32) ? 16 + (qt - 16) * 2
           : (qt < 48) ? 48 + (qt - 32) * 3 : 96 + (qt - 48) * 4;
  int p0 = bh * 160 + base;
  int q  = threadIdx.x >> 3;
  int d  = (threadIdx.x & 7) * 8;

  float L = pML[p0 * 32 + q] + pML[(p0 + 1) * 32 + q];
  if (nc > 2) L += pML[(p0 + 2) * 32 + q];
  if (nc > 3) L += pML[(p0 + 3) * 32 + q];
  float invL = 1.0f / L;

  float o[8];
  short8 v0 = *reinterpret_cast<const short8*>(&pO[(size_t)p0 * 2048 + q * 64 + d]);
  short8 v1 = *reinterpret_cast<const short8*>(&pO[(size_t)(p0 + 1) * 2048 + q * 64 + d]);
  #pragma unroll
  for (int jj = 0; jj < 8; jj++) o[jj] = bf2f((u16)v0[jj]) + bf2f((u16)v1[jj]);
  if (nc > 2) {
    short8 v = *reinterpret_cast<const short8*>(&pO[(size_t)(p0 + 2) * 2048 + q * 64 + d]);
    #pragma unroll
    for (int jj = 0; jj < 8; jj++) o[jj] += bf2f((u16)v[jj]);
  }
  if (nc > 3) {
    short8 v = *reinterpret_cast<const short8*>(&pO[(size_t)(p0 + 3) * 2048 + q * 64 + d]);
    #pragma unroll
    for (int jj = 0; jj < 8; jj++) o[jj] += bf2f((u16)v[jj]);
  }
  short8 ov;
  #pragma unroll
  for (int jj = 0; jj < 8; jj++) ov[jj] = (short)f2bf(o[jj] * invL);
  *reinterpret_cast<short8*>(
      &att[((size_t)(b * S_ + qt * 32 + q)) * D_ + hd * 64 + d]) = ov;
}

// ---------------- host launch ----------------
extern "C" void kernel_launch(void* const* d_in, const int* in_sizes, int n_in,
                              void* d_out, int out_size, void* d_ws, size_t ws_size,
                              hipStream_t stream) {
  (void)in_sizes; (void)n_in; (void)out_size; (void)ws_size;
  const float* x    = (const float*)d_in[0];
  const float* Wq   = (const float*)d_in[1];
  const float* Wk   = (const float*)d_in[2];
  const float* Wv   = (const float*)d_in[3];
  const float* Wo   = (const float*)d_in[4];
  const float* Wff  = (const float*)d_in[5];
  const float* Wout = (const float*)d_in[6];
  float* out = (float*)d_out;

  char* ws = (char*)d_ws;
  u16*   wqkv = (u16*)(ws);                    // [3072,1024] bf16, 6MB
  u16*   wo   = (u16*)(ws + 6291456);          // [1024,1024], 2MB
  u16*   wff  = (u16*)(ws + 8388608);          // [8192,1024], 16MB
  u16*   wout = (u16*)(ws + 25165824);         // [1024,4096], 8MB
  float* x1   = (float*)(ws + 33554432);       // [4096,1024] f32, 16MB
  char*  P    = ws + 50331648;                 // reuse pool
  u16*   hbuf = (u16*)(P);                     // [4096,1024], 8MB
  u16*   qkv  = (u16*)(P + 8388608);           // [4096,3072], 24MB
  u16*   vT   = (u16*)(P + 33554432);          // [32,64,2048], 8MB
  u16*   att  = (u16*)(P + 41943040);          // [4096,1024], 8MB
  u16*   pO   = (u16*)(P + 50331648);          // [5120,2048] bf16, 21MB (attn phase)
  float* pML  = (float*)(P + 71303168);        // [5120,32] f32, 640KB
  u16*   h2   = (u16*)(P);                     // reuse hbuf slot
  u16*   gbuf = (u16*)(P + 41943040);          // [4096,4096], 32MB (over att+pO head)

  conv_ln<<<20480, 256, 0, stream>>>(Wq, Wk, Wv, Wo, Wff, Wout,
                                     wqkv, wo, wff, wout, x, hbuf);

  gemm_bt2<0><<<dim3(768), 256, 0, stream>>>(hbuf, wqkv, qkv, nullptr, M_, 3072, 1024);
  transpose_v<<<dim3(32, 32), 256, 0, stream>>>(qkv, vT);
  attn_split<<<dim3(1280), 256, 0, stream>>>(qkv, vT, pO, pML, att);
  attn_combine<<<dim3(1536), 256, 0, stream>>>(pO, pML, att);
  gemm_bt2h<1><<<dim3(512), 256, 0, stream>>>(att, wo, x1, x, M_, 1024, 1024);

  ln_rows<<<M_, 256, 0, stream>>>(x1, h2);
  gemm_ff<<<dim3(1024), 256, 0, stream>>>(h2, wff, gbuf, M_, 4096, 1024);
  gemm_bt2h<1><<<dim3(512), 256, 0, stream>>>(gbuf, wout, out, x1, M_, 1024, 4096);
}